// Round 1
// baseline (341.192 us; speedup 1.0000x reference)
//
#include <hip/hip_runtime.h>
#include <cstdint>
#include <cstddef>

#define NV    8192   // nodes
#define KIN   512    // in features
#define MOUT  128    // out features
#define NTILE (NV / 64)

typedef __attribute__((ext_vector_type(4))) float f32x4;
typedef __attribute__((ext_vector_type(8))) short short8;

__device__ __forceinline__ unsigned short f2bf(float x) {
  unsigned int u = __float_as_uint(x);
  return (unsigned short)((u + 0x7fffu + ((u >> 16) & 1u)) >> 16);  // RNE
}
__device__ __forceinline__ float elu1(float x) { return x > 0.f ? x : expm1f(x); }

// ---------------- kernel 1: wh = h @ w^T  (fp32) + fused wh1/wh2 ----------------
// grid 256 blocks x 256 thr; block = 32 rows x 128 cols, K-tiles of 64.
__global__ __launch_bounds__(256) void k_wh(const float* __restrict__ h,
                                            const float* __restrict__ w,
                                            const float* __restrict__ a1,
                                            const float* __restrict__ a2,
                                            float* __restrict__ wh,
                                            float* __restrict__ wh1,
                                            float* __restrict__ wh2) {
  __shared__ __align__(16) float hT[64][36];    // [k][row], pad 36: b128-aligned rows
  __shared__ __align__(16) float wT[64][128];   // [k][col]
  const int t = threadIdx.x;
  const int row0 = blockIdx.x * 32;
  const int hr = t >> 3, hu = t & 7;            // h-load mapping
  const int wc = t >> 1, whalf = t & 1;         // w-load mapping
  const int cg = t & 31, rg = t >> 5;           // gemm mapping
  const int c0 = cg * 4, r0 = rg * 4;
  float acc[4][4] = {};

  for (int kt = 0; kt < 8; ++kt) {
    const int k0 = kt * 64;
    __syncthreads();
#pragma unroll
    for (int v = 0; v < 8; ++v)                 // strided k per thread: 2-way banks
      hT[hu + 8 * v][hr] = h[(size_t)(row0 + hr) * KIN + k0 + hu + 8 * v];
#pragma unroll
    for (int mv = 0; mv < 8; ++mv) {
      const float4 wv = *(const float4*)&w[(size_t)wc * KIN + k0 + whalf * 32 + mv * 4];
      wT[whalf * 32 + mv * 4 + 0][wc] = wv.x;
      wT[whalf * 32 + mv * 4 + 1][wc] = wv.y;
      wT[whalf * 32 + mv * 4 + 2][wc] = wv.z;
      wT[whalf * 32 + mv * 4 + 3][wc] = wv.w;
    }
    __syncthreads();
#pragma unroll 8
    for (int kk = 0; kk < 64; ++kk) {
      const float4 hv = *(const float4*)&hT[kk][r0];
      const float4 wv = *(const float4*)&wT[kk][c0];
      const float hvv[4] = {hv.x, hv.y, hv.z, hv.w};
      const float wvv[4] = {wv.x, wv.y, wv.z, wv.w};
#pragma unroll
      for (int i = 0; i < 4; ++i)
#pragma unroll
        for (int j = 0; j < 4; ++j)
          acc[i][j] = fmaf(hvv[i], wvv[j], acc[i][j]);
    }
  }

  const float4 a1v = *(const float4*)&a1[c0];
  const float4 a2v = *(const float4*)&a2[c0];
#pragma unroll
  for (int i = 0; i < 4; ++i) {
    float4 o;
    o.x = acc[i][0]; o.y = acc[i][1]; o.z = acc[i][2]; o.w = acc[i][3];
    *(float4*)&wh[(size_t)(row0 + r0 + i) * MOUT + c0] = o;
    float s1 = acc[i][0] * a1v.x + acc[i][1] * a1v.y + acc[i][2] * a1v.z + acc[i][3] * a1v.w;
    float s2 = acc[i][0] * a2v.x + acc[i][1] * a2v.y + acc[i][2] * a2v.z + acc[i][3] * a2v.w;
#pragma unroll
    for (int off = 16; off > 0; off >>= 1) {
      s1 += __shfl_down(s1, off, 32);
      s2 += __shfl_down(s2, off, 32);
    }
    if (cg == 0) {
      wh1[row0 + r0 + i] = s1;
      wh2[row0 + r0 + i] = s2;
    }
  }
}

// ---------------- kernel 2: whT[c][j] = bf16(wh[j][c])  (128 x 8192) ----------------
// grid 128 blocks x 256 thr; tile = 64 j-rows, all 128 cols.
__global__ __launch_bounds__(256) void k_tr(const float* __restrict__ wh,
                                            unsigned short* __restrict__ whT) {
  __shared__ __align__(16) unsigned short ldsT[128][72];
  const int t = threadIdx.x;
  const int j0 = blockIdx.x * 64;
  {
    const int jr = t >> 2, q = t & 3;
#pragma unroll
    for (int mv = 0; mv < 8; ++mv) {
      const float4 v = *(const float4*)&wh[(size_t)(j0 + jr) * MOUT + q * 32 + mv * 4];
      ldsT[q * 32 + mv * 4 + 0][jr] = f2bf(v.x);
      ldsT[q * 32 + mv * 4 + 1][jr] = f2bf(v.y);
      ldsT[q * 32 + mv * 4 + 2][jr] = f2bf(v.z);
      ldsT[q * 32 + mv * 4 + 3][jr] = f2bf(v.w);
    }
  }
  __syncthreads();
  {
    const int c = t >> 1, half = t & 1;
#pragma unroll
    for (int m = 0; m < 4; ++m) {
      const short8 v = *(const short8*)&ldsT[c][half * 32 + m * 8];
      *(short8*)&whT[(size_t)c * NV + j0 + half * 32 + m * 8] = v;
    }
  }
}

// ---------------- kernel 3: fused masked-softmax attention + PV (bf16 MFMA) ----------------
// grid 256 blocks x 256 thr; block = 32 rows (i), loop over 128 j-tiles of 64.
// Scores fully fp32; P and wh values cast bf16 for mfma_f32_16x16x32_bf16.
__global__ __launch_bounds__(256) void k_attn(const unsigned short* __restrict__ whT,
                                              const int* __restrict__ adj,
                                              const float* __restrict__ wh1,
                                              const float* __restrict__ wh2,
                                              float* __restrict__ out) {
  __shared__ __align__(16) unsigned short Bt[128][72];  // whT tile [c][j], pad 72
  __shared__ __align__(16) unsigned short Pt[32][72];   // P tile  [i][j], pad 72
  __shared__ float sum_lds[32];
  const int t = threadIdx.x;
  const int i0 = blockIdx.x * 32;
  const int pi = t >> 3, pq = t & 7;        // P-compute mapping: row pi, 8 contig j
  const int bc = t >> 1, bhalf = t & 1;     // B-stage mapping: row bc, 64B half
  const int lid = t & 63, wv = t >> 6;      // mfma mapping
  const int l15 = lid & 15, lg = lid >> 4;

  const float wh1r = wh1[i0 + pi];
  const int* aptr = adj + (size_t)(i0 + pi) * NV;
  f32x4 acc[2][2] = {};
  float psum = 0.f;

  // prefetch tile 0 (adj + B) into registers
  int4 av0 = *(const int4*)&aptr[pq * 8];
  int4 av1 = *(const int4*)&aptr[pq * 8 + 4];
  float4 br[4];
#pragma unroll
  for (int m = 0; m < 4; ++m)
    br[m] = *(const float4*)&whT[(size_t)bc * NV + bhalf * 32 + m * 8];

  for (int tile = 0; tile < NTILE; ++tile) {
    const int j0 = tile * 64;
    __syncthreads();  // previous MFMA reads of Bt/Pt done
    // stage B tile from prefetched regs
#pragma unroll
    for (int m = 0; m < 4; ++m)
      *(float4*)&Bt[bc][bhalf * 32 + m * 8] = br[m];
    // compute P tile (f32 scores, bf16 pack)
    {
      const float4 w2a = *(const float4*)&wh2[j0 + pq * 8];
      const float4 w2b = *(const float4*)&wh2[j0 + pq * 8 + 4];
      const int aarr[8] = {av0.x, av0.y, av0.z, av0.w, av1.x, av1.y, av1.z, av1.w};
      const float w2arr[8] = {w2a.x, w2a.y, w2a.z, w2a.w, w2b.x, w2b.y, w2b.z, w2b.w};
      short8 pv;
#pragma unroll
      for (int u = 0; u < 8; ++u) {
        float e = wh1r + w2arr[u];
        e = e > 0.f ? e : 0.01f * e;               // leaky relu
        const float p = (aarr[u] > 0) ? __expf(e) : 0.f;  // mask -> exact 0
        psum += p;
        pv[u] = (short)f2bf(p);
      }
      *(short8*)&Pt[pi][pq * 8] = pv;
    }
    // prefetch next tile (hidden under MFMA phase)
    if (tile + 1 < NTILE) {
      const int j1 = j0 + 64;
      av0 = *(const int4*)&aptr[j1 + pq * 8];
      av1 = *(const int4*)&aptr[j1 + pq * 8 + 4];
#pragma unroll
      for (int m = 0; m < 4; ++m)
        br[m] = *(const float4*)&whT[(size_t)bc * NV + j1 + bhalf * 32 + m * 8];
    }
    __syncthreads();
    // MFMA: acc[ih][ct] over 32 rows x 32 cols per wave (wave wv owns cols wv*32..+31)
#pragma unroll
    for (int ks = 0; ks < 2; ++ks) {
      const short8 a0 = *(const short8*)&Pt[l15][ks * 32 + lg * 8];
      const short8 a1f = *(const short8*)&Pt[16 + l15][ks * 32 + lg * 8];
      const short8 b0 = *(const short8*)&Bt[wv * 32 + l15][ks * 32 + lg * 8];
      const short8 b1f = *(const short8*)&Bt[wv * 32 + 16 + l15][ks * 32 + lg * 8];
      acc[0][0] = __builtin_amdgcn_mfma_f32_16x16x32_bf16(a0, b0, acc[0][0], 0, 0, 0);
      acc[0][1] = __builtin_amdgcn_mfma_f32_16x16x32_bf16(a0, b1f, acc[0][1], 0, 0, 0);
      acc[1][0] = __builtin_amdgcn_mfma_f32_16x16x32_bf16(a1f, b0, acc[1][0], 0, 0, 0);
      acc[1][1] = __builtin_amdgcn_mfma_f32_16x16x32_bf16(a1f, b1f, acc[1][1], 0, 0, 0);
    }
  }

  // row sums: reduce psum over the 8 pq-lanes of each row
#pragma unroll
  for (int off = 4; off > 0; off >>= 1) psum += __shfl_down(psum, off, 8);
  if (pq == 0) sum_lds[pi] = psum;
  __syncthreads();

  // epilogue: normalize + ELU + store (C/D layout: col=lane&15, row=(lane>>4)*4+reg)
#pragma unroll
  for (int ih = 0; ih < 2; ++ih)
#pragma unroll
    for (int ct = 0; ct < 2; ++ct)
#pragma unroll
      for (int r = 0; r < 4; ++r) {
        const int row = 16 * ih + lg * 4 + r;
        const float v = acc[ih][ct][r] * (1.f / sum_lds[row]);
        out[(size_t)(i0 + row) * MOUT + wv * 32 + 16 * ct + l15] = elu1(v);
      }
}

extern "C" void kernel_launch(void* const* d_in, const int* in_sizes, int n_in,
                              void* d_out, int out_size, void* d_ws, size_t ws_size,
                              hipStream_t stream) {
  const float* h  = (const float*)d_in[0];
  const int* adj  = (const int*)d_in[1];
  const float* w  = (const float*)d_in[2];
  const float* a1 = (const float*)d_in[3];
  const float* a2 = (const float*)d_in[4];
  float* out = (float*)d_out;

  char* ws = (char*)d_ws;
  float* wh = (float*)ws;                                        // 4 MB f32 [8192][128]
  unsigned short* whT = (unsigned short*)(ws + (size_t)NV * MOUT * 4);  // 2 MB bf16 [128][8192]
  float* wh1 = (float*)(ws + (size_t)NV * MOUT * 4 + (size_t)MOUT * NV * 2);
  float* wh2 = wh1 + NV;

  k_wh<<<NV / 32, 256, 0, stream>>>(h, w, a1, a2, wh, wh1, wh2);
  k_tr<<<NV / 64, 256, 0, stream>>>(wh, whT);
  k_attn<<<NV / 32, 256, 0, stream>>>(whT, adj, wh1, wh2, out);
}

// Round 2
// 305.440 us; speedup vs baseline: 1.1171x; 1.1171x over previous
//
#include <hip/hip_runtime.h>
#include <cstdint>
#include <cstddef>

#define NV    8192   // nodes
#define KIN   512    // in features
#define MOUT  128    // out features

typedef __attribute__((ext_vector_type(4))) float f32x4;
typedef __attribute__((ext_vector_type(8))) short short8;

__device__ __forceinline__ unsigned short f2bf(float x) {
  unsigned int u = __float_as_uint(x);
  return (unsigned short)((u + 0x7fffu + ((u >> 16) & 1u)) >> 16);  // RNE
}
__device__ __forceinline__ float elu1(float x) { return x > 0.f ? x : expm1f(x); }

// ---------------- kernel 1: wh = h @ w^T  (fp32) + fused wh1/wh2 ----------------
__global__ __launch_bounds__(256) void k_wh(const float* __restrict__ h,
                                            const float* __restrict__ w,
                                            const float* __restrict__ a1,
                                            const float* __restrict__ a2,
                                            float* __restrict__ wh,
                                            float* __restrict__ wh1,
                                            float* __restrict__ wh2) {
  __shared__ __align__(16) float hT[64][36];
  __shared__ __align__(16) float wT[64][128];
  const int t = threadIdx.x;
  const int row0 = blockIdx.x * 32;
  const int hr = t >> 3, hu = t & 7;
  const int wc = t >> 1, whalf = t & 1;
  const int cg = t & 31, rg = t >> 5;
  const int c0 = cg * 4, r0 = rg * 4;
  float acc[4][4] = {};

  for (int kt = 0; kt < 8; ++kt) {
    const int k0 = kt * 64;
    __syncthreads();
#pragma unroll
    for (int v = 0; v < 8; ++v)
      hT[hu + 8 * v][hr] = h[(size_t)(row0 + hr) * KIN + k0 + hu + 8 * v];
#pragma unroll
    for (int mv = 0; mv < 8; ++mv) {
      const float4 wv = *(const float4*)&w[(size_t)wc * KIN + k0 + whalf * 32 + mv * 4];
      wT[whalf * 32 + mv * 4 + 0][wc] = wv.x;
      wT[whalf * 32 + mv * 4 + 1][wc] = wv.y;
      wT[whalf * 32 + mv * 4 + 2][wc] = wv.z;
      wT[whalf * 32 + mv * 4 + 3][wc] = wv.w;
    }
    __syncthreads();
#pragma unroll 8
    for (int kk = 0; kk < 64; ++kk) {
      const float4 hv = *(const float4*)&hT[kk][r0];
      const float4 wv = *(const float4*)&wT[kk][c0];
      const float hvv[4] = {hv.x, hv.y, hv.z, hv.w};
      const float wvv[4] = {wv.x, wv.y, wv.z, wv.w};
#pragma unroll
      for (int i = 0; i < 4; ++i)
#pragma unroll
        for (int j = 0; j < 4; ++j)
          acc[i][j] = fmaf(hvv[i], wvv[j], acc[i][j]);
    }
  }

  const float4 a1v = *(const float4*)&a1[c0];
  const float4 a2v = *(const float4*)&a2[c0];
#pragma unroll
  for (int i = 0; i < 4; ++i) {
    float4 o;
    o.x = acc[i][0]; o.y = acc[i][1]; o.z = acc[i][2]; o.w = acc[i][3];
    *(float4*)&wh[(size_t)(row0 + r0 + i) * MOUT + c0] = o;
    float s1 = acc[i][0] * a1v.x + acc[i][1] * a1v.y + acc[i][2] * a1v.z + acc[i][3] * a1v.w;
    float s2 = acc[i][0] * a2v.x + acc[i][1] * a2v.y + acc[i][2] * a2v.z + acc[i][3] * a2v.w;
#pragma unroll
    for (int off = 16; off > 0; off >>= 1) {
      s1 += __shfl_down(s1, off, 32);
      s2 += __shfl_down(s2, off, 32);
    }
    if (cg == 0) {
      wh1[row0 + r0 + i] = s1;
      wh2[row0 + r0 + i] = s2;
    }
  }
}

// ---------------- kernel 2: whT[c][j] = bf16(wh[j][c]) ----------------
__global__ __launch_bounds__(256) void k_tr(const float* __restrict__ wh,
                                            unsigned short* __restrict__ whT) {
  __shared__ __align__(16) unsigned short ldsT[128][72];
  const int t = threadIdx.x;
  const int j0 = blockIdx.x * 64;
  {
    const int jr = t >> 2, q = t & 3;
#pragma unroll
    for (int mv = 0; mv < 8; ++mv) {
      const float4 v = *(const float4*)&wh[(size_t)(j0 + jr) * MOUT + q * 32 + mv * 4];
      ldsT[q * 32 + mv * 4 + 0][jr] = f2bf(v.x);
      ldsT[q * 32 + mv * 4 + 1][jr] = f2bf(v.y);
      ldsT[q * 32 + mv * 4 + 2][jr] = f2bf(v.z);
      ldsT[q * 32 + mv * 4 + 3][jr] = f2bf(v.w);
    }
  }
  __syncthreads();
  {
    const int c = t >> 1, half = t & 1;
#pragma unroll
    for (int m = 0; m < 4; ++m) {
      const short8 v = *(const short8*)&ldsT[c][half * 32 + m * 8];
      *(short8*)&whT[(size_t)c * NV + j0 + half * 32 + m * 8] = v;
    }
  }
}

// ---------------- kernel 3: partial masked-softmax attention + PV (bf16 MFMA) ----------------
// grid (256, S) x 256 thr; block = 32 rows (i) x ntiles*64 j-slice (blockIdx.y-th slice).
// Writes UNNORMALIZED partial PV accumulation + partial row sums.
__global__ __launch_bounds__(256) void k_attn_p(const unsigned short* __restrict__ whT,
                                                const int* __restrict__ adj,
                                                const float* __restrict__ wh1,
                                                const float* __restrict__ wh2,
                                                float* __restrict__ out_p,
                                                float* __restrict__ psum_p,
                                                int ntiles) {
  __shared__ __align__(16) unsigned short Bt[128][72];
  __shared__ __align__(16) unsigned short Pt[32][72];
  const int t = threadIdx.x;
  const int i0 = blockIdx.x * 32;
  const int jbase = blockIdx.y * ntiles * 64;
  const int pi = t >> 3, pq = t & 7;
  const int bc = t >> 1, bhalf = t & 1;
  const int lid = t & 63, wv = t >> 6;
  const int l15 = lid & 15, lg = lid >> 4;

  const float wh1r = wh1[i0 + pi];
  const int* aptr = adj + (size_t)(i0 + pi) * NV;
  f32x4 acc[2][2] = {};
  float psum = 0.f;

  // prefetch tile 0 (adj + B) into registers
  int4 av0 = *(const int4*)&aptr[jbase + pq * 8];
  int4 av1 = *(const int4*)&aptr[jbase + pq * 8 + 4];
  float4 br[4];
#pragma unroll
  for (int m = 0; m < 4; ++m)
    br[m] = *(const float4*)&whT[(size_t)bc * NV + jbase + bhalf * 32 + m * 8];

  for (int tile = 0; tile < ntiles; ++tile) {
    const int j0 = jbase + tile * 64;
    __syncthreads();
#pragma unroll
    for (int m = 0; m < 4; ++m)
      *(float4*)&Bt[bc][bhalf * 32 + m * 8] = br[m];
    {
      const float4 w2a = *(const float4*)&wh2[j0 + pq * 8];
      const float4 w2b = *(const float4*)&wh2[j0 + pq * 8 + 4];
      const int aarr[8] = {av0.x, av0.y, av0.z, av0.w, av1.x, av1.y, av1.z, av1.w};
      const float w2arr[8] = {w2a.x, w2a.y, w2a.z, w2a.w, w2b.x, w2b.y, w2b.z, w2b.w};
      short8 pv;
#pragma unroll
      for (int u = 0; u < 8; ++u) {
        float e = wh1r + w2arr[u];
        e = e > 0.f ? e : 0.01f * e;
        const float p = (aarr[u] > 0) ? __expf(e) : 0.f;
        psum += p;
        pv[u] = (short)f2bf(p);
      }
      *(short8*)&Pt[pi][pq * 8] = pv;
    }
    if (tile + 1 < ntiles) {
      const int j1 = j0 + 64;
      av0 = *(const int4*)&aptr[j1 + pq * 8];
      av1 = *(const int4*)&aptr[j1 + pq * 8 + 4];
#pragma unroll
      for (int m = 0; m < 4; ++m)
        br[m] = *(const float4*)&whT[(size_t)bc * NV + j1 + bhalf * 32 + m * 8];
    }
    __syncthreads();
#pragma unroll
    for (int ks = 0; ks < 2; ++ks) {
      const short8 a0 = *(const short8*)&Pt[l15][ks * 32 + lg * 8];
      const short8 a1f = *(const short8*)&Pt[16 + l15][ks * 32 + lg * 8];
      const short8 b0 = *(const short8*)&Bt[wv * 32 + l15][ks * 32 + lg * 8];
      const short8 b1f = *(const short8*)&Bt[wv * 32 + 16 + l15][ks * 32 + lg * 8];
      acc[0][0] = __builtin_amdgcn_mfma_f32_16x16x32_bf16(a0, b0, acc[0][0], 0, 0, 0);
      acc[0][1] = __builtin_amdgcn_mfma_f32_16x16x32_bf16(a0, b1f, acc[0][1], 0, 0, 0);
      acc[1][0] = __builtin_amdgcn_mfma_f32_16x16x32_bf16(a1f, b0, acc[1][0], 0, 0, 0);
      acc[1][1] = __builtin_amdgcn_mfma_f32_16x16x32_bf16(a1f, b1f, acc[1][1], 0, 0, 0);
    }
  }

  // partial row sums over this j-slice
#pragma unroll
  for (int off = 4; off > 0; off >>= 1) psum += __shfl_down(psum, off, 8);
  if (pq == 0) psum_p[(size_t)blockIdx.y * NV + i0 + pi] = psum;

  // unnormalized partial PV tile (C/D layout: col=lane&15, row=(lane>>4)*4+reg)
#pragma unroll
  for (int ih = 0; ih < 2; ++ih)
#pragma unroll
    for (int ct = 0; ct < 2; ++ct)
#pragma unroll
      for (int r = 0; r < 4; ++r) {
        const int row = 16 * ih + lg * 4 + r;
        out_p[((size_t)blockIdx.y * NV + i0 + row) * MOUT + wv * 32 + 16 * ct + l15] =
            acc[ih][ct][r];
      }
}

// ---------------- kernel 4: combine partials, normalize, ELU ----------------
__global__ __launch_bounds__(256) void k_comb(const float* __restrict__ out_p,
                                              const float* __restrict__ psum_p,
                                              float* __restrict__ out, int S) {
  const int idx = (blockIdx.x * 256 + threadIdx.x) * 4;
  const int n = idx >> 7;  // MOUT = 128
  float denom = 0.f;
  for (int s = 0; s < S; ++s) denom += psum_p[(size_t)s * NV + n];
  float4 acc = {0.f, 0.f, 0.f, 0.f};
  for (int s = 0; s < S; ++s) {
    const float4 v = *(const float4*)&out_p[(size_t)s * NV * MOUT + idx];
    acc.x += v.x; acc.y += v.y; acc.z += v.z; acc.w += v.w;
  }
  const float inv = 1.f / denom;
  float4 o;
  o.x = elu1(acc.x * inv);
  o.y = elu1(acc.y * inv);
  o.z = elu1(acc.z * inv);
  o.w = elu1(acc.w * inv);
  *(float4*)&out[idx] = o;
}

extern "C" void kernel_launch(void* const* d_in, const int* in_sizes, int n_in,
                              void* d_out, int out_size, void* d_ws, size_t ws_size,
                              hipStream_t stream) {
  const float* h  = (const float*)d_in[0];
  const int* adj  = (const int*)d_in[1];
  const float* w  = (const float*)d_in[2];
  const float* a1 = (const float*)d_in[3];
  const float* a2 = (const float*)d_in[4];
  float* out = (float*)d_out;

  char* ws = (char*)d_ws;
  // layout: [whT 2MB][wh1 32KB][wh2 32KB][psum_p 8*32KB][region: wh (4MB) aliases out_p slab 0]
  unsigned short* whT = (unsigned short*)ws;
  size_t off = (size_t)MOUT * NV * 2;
  float* wh1 = (float*)(ws + off); off += (size_t)NV * 4;
  float* wh2 = (float*)(ws + off); off += (size_t)NV * 4;
  float* psum_p = (float*)(ws + off); off += (size_t)8 * NV * 4;
  float* region = (float*)(ws + off);
  float* wh = region;      // dead after k_tr
  float* out_p = region;   // S slabs of [NV][MOUT] f32

  int S = 8;
  while (S > 1 && off + (size_t)S * NV * MOUT * 4 > ws_size) S >>= 1;

  k_wh<<<NV / 32, 256, 0, stream>>>(h, w, a1, a2, wh, wh1, wh2);
  k_tr<<<NV / 64, 256, 0, stream>>>(wh, whT);
  k_attn_p<<<dim3(NV / 32, S), 256, 0, stream>>>(whT, adj, wh1, wh2, out_p, psum_p, 128 / S);
  k_comb<<<(NV * MOUT / 4) / 256, 256, 0, stream>>>(out_p, psum_p, out, S);
}

// Round 3
// 250.328 us; speedup vs baseline: 1.3630x; 1.2202x over previous
//
#include <hip/hip_runtime.h>
#include <cstdint>
#include <cstddef>

#define NV    8192   // nodes
#define KIN   512    // in features
#define MOUT  128    // out features

typedef __attribute__((ext_vector_type(4))) float f32x4;
typedef __attribute__((ext_vector_type(8))) short short8;

__device__ __forceinline__ unsigned short f2bf(float x) {
  unsigned int u = __float_as_uint(x);
  return (unsigned short)((u + 0x7fffu + ((u >> 16) & 1u)) >> 16);  // RNE
}
__device__ __forceinline__ float elu1(float x) { return x > 0.f ? x : expm1f(x); }

// ---------------- kernel 1: wh = h @ w^T  (fp32) + fused wh1/wh2 ----------------
__global__ __launch_bounds__(256) void k_wh(const float* __restrict__ h,
                                            const float* __restrict__ w,
                                            const float* __restrict__ a1,
                                            const float* __restrict__ a2,
                                            float* __restrict__ wh,
                                            float* __restrict__ wh1,
                                            float* __restrict__ wh2) {
  __shared__ __align__(16) float hT[64][36];
  __shared__ __align__(16) float wT[64][128];
  const int t = threadIdx.x;
  const int row0 = blockIdx.x * 32;
  const int hr = t >> 3, hu = t & 7;
  const int wc = t >> 1, whalf = t & 1;
  const int cg = t & 31, rg = t >> 5;
  const int c0 = cg * 4, r0 = rg * 4;
  float acc[4][4] = {};

  for (int kt = 0; kt < 8; ++kt) {
    const int k0 = kt * 64;
    __syncthreads();
#pragma unroll
    for (int v = 0; v < 8; ++v)
      hT[hu + 8 * v][hr] = h[(size_t)(row0 + hr) * KIN + k0 + hu + 8 * v];
#pragma unroll
    for (int mv = 0; mv < 8; ++mv) {
      const float4 wv = *(const float4*)&w[(size_t)wc * KIN + k0 + whalf * 32 + mv * 4];
      wT[whalf * 32 + mv * 4 + 0][wc] = wv.x;
      wT[whalf * 32 + mv * 4 + 1][wc] = wv.y;
      wT[whalf * 32 + mv * 4 + 2][wc] = wv.z;
      wT[whalf * 32 + mv * 4 + 3][wc] = wv.w;
    }
    __syncthreads();
#pragma unroll 8
    for (int kk = 0; kk < 64; ++kk) {
      const float4 hv = *(const float4*)&hT[kk][r0];
      const float4 wv = *(const float4*)&wT[kk][c0];
      const float hvv[4] = {hv.x, hv.y, hv.z, hv.w};
      const float wvv[4] = {wv.x, wv.y, wv.z, wv.w};
#pragma unroll
      for (int i = 0; i < 4; ++i)
#pragma unroll
        for (int j = 0; j < 4; ++j)
          acc[i][j] = fmaf(hvv[i], wvv[j], acc[i][j]);
    }
  }

  const float4 a1v = *(const float4*)&a1[c0];
  const float4 a2v = *(const float4*)&a2[c0];
#pragma unroll
  for (int i = 0; i < 4; ++i) {
    float4 o;
    o.x = acc[i][0]; o.y = acc[i][1]; o.z = acc[i][2]; o.w = acc[i][3];
    *(float4*)&wh[(size_t)(row0 + r0 + i) * MOUT + c0] = o;
    float s1 = acc[i][0] * a1v.x + acc[i][1] * a1v.y + acc[i][2] * a1v.z + acc[i][3] * a1v.w;
    float s2 = acc[i][0] * a2v.x + acc[i][1] * a2v.y + acc[i][2] * a2v.z + acc[i][3] * a2v.w;
#pragma unroll
    for (int off = 16; off > 0; off >>= 1) {
      s1 += __shfl_down(s1, off, 32);
      s2 += __shfl_down(s2, off, 32);
    }
    if (cg == 0) {
      wh1[row0 + r0 + i] = s1;
      wh2[row0 + r0 + i] = s2;
    }
  }
}

// ---------------- kernel 2: whT[c][j] = bf16(wh[j][c]) ----------------
__global__ __launch_bounds__(256) void k_tr(const float* __restrict__ wh,
                                            unsigned short* __restrict__ whT) {
  __shared__ __align__(16) unsigned short ldsT[128][72];
  const int t = threadIdx.x;
  const int j0 = blockIdx.x * 64;
  {
    const int jr = t >> 2, q = t & 3;
#pragma unroll
    for (int mv = 0; mv < 8; ++mv) {
      const float4 v = *(const float4*)&wh[(size_t)(j0 + jr) * MOUT + q * 32 + mv * 4];
      ldsT[q * 32 + mv * 4 + 0][jr] = f2bf(v.x);
      ldsT[q * 32 + mv * 4 + 1][jr] = f2bf(v.y);
      ldsT[q * 32 + mv * 4 + 2][jr] = f2bf(v.z);
      ldsT[q * 32 + mv * 4 + 3][jr] = f2bf(v.w);
    }
  }
  __syncthreads();
  {
    const int c = t >> 1, half = t & 1;
#pragma unroll
    for (int m = 0; m < 4; ++m) {
      const short8 v = *(const short8*)&ldsT[c][half * 32 + m * 8];
      *(short8*)&whT[(size_t)c * NV + j0 + half * 32 + m * 8] = v;
    }
  }
}

// ---------------- kernel 2b: bit-pack adjacency: maskb[i][j/8] bit j%8 ----------------
// grid 2048 x 256; block = 4 rows, wave w owns row blockIdx.x*4+w; pure stream.
__global__ __launch_bounds__(256) void k_pack(const int* __restrict__ adj,
                                              unsigned char* __restrict__ maskb) {
  const int t = threadIdx.x;
  const int w = t >> 6, l = t & 63;
  const int row = blockIdx.x * 4 + w;
  const int* ap = adj + (size_t)row * NV;
  unsigned char* mp = maskb + (size_t)row * (NV / 8);
#pragma unroll
  for (int it = 0; it < NV / 512; ++it) {   // 16 iters, 512 j per wave-iter
    const int j = it * 512 + l * 8;
    const int4 a = *(const int4*)&ap[j];
    const int4 b = *(const int4*)&ap[j + 4];
    unsigned int byte =
        ((a.x > 0) ? 1u : 0u)  | ((a.y > 0) ? 2u : 0u)  |
        ((a.z > 0) ? 4u : 0u)  | ((a.w > 0) ? 8u : 0u)  |
        ((b.x > 0) ? 16u : 0u) | ((b.y > 0) ? 32u : 0u) |
        ((b.z > 0) ? 64u : 0u) | ((b.w > 0) ? 128u : 0u);
    mp[it * 64 + l] = (unsigned char)byte;
  }
}

// ---------------- kernel 3: partial masked-softmax attention + PV (bf16 MFMA) ----------------
// grid (256, S) x 256 thr; block = 32 rows (i) x ntiles*64 j-slice.
// Writes UNNORMALIZED partial PV + partial row sums. Reads bitmask, not adj.
__global__ __launch_bounds__(256) void k_attn_p(const unsigned short* __restrict__ whT,
                                                const unsigned char* __restrict__ maskb,
                                                const float* __restrict__ wh1,
                                                const float* __restrict__ wh2,
                                                float* __restrict__ out_p,
                                                float* __restrict__ psum_p,
                                                int ntiles) {
  union SMem {
    struct { unsigned short Bt[128][72]; unsigned short Pt[32][72]; } s;
    float epi[32][132];   // 16.9 KB <= 23 KB, aliases Bt/Pt after main loop
  };
  __shared__ SMem sm;
  const int t = threadIdx.x;
  const int i0 = blockIdx.x * 32;
  const int jbase = blockIdx.y * ntiles * 64;
  const int pi = t >> 3, pq = t & 7;        // P-compute: row pi, 8 j's
  const int brow = t >> 3, bjq = t & 7;     // B-stage: rows brow+32m, 8 j-floats each
  const int lid = t & 63, wv = t >> 6;      // mfma mapping
  const int l15 = lid & 15, lg = lid >> 4;

  const float wh1r = wh1[i0 + pi];
  const unsigned char* mp = maskb + (size_t)(i0 + pi) * (NV / 8) + jbase / 8;
  f32x4 acc[2][2] = {};
  float psum = 0.f;

  // prefetch tile 0: mask byte + B tile + wh2
  unsigned int mcur = mp[pq];
  float4 br[4];
#pragma unroll
  for (int m = 0; m < 4; ++m)
    br[m] = *(const float4*)&whT[(size_t)(brow + 32 * m) * NV + jbase + bjq * 8];
  float4 w2a = *(const float4*)&wh2[jbase + pq * 8];
  float4 w2b = *(const float4*)&wh2[jbase + pq * 8 + 4];

  for (int tile = 0; tile < ntiles; ++tile) {
    __syncthreads();  // previous MFMA reads of Bt/Pt done
    // stage B tile from prefetched regs
#pragma unroll
    for (int m = 0; m < 4; ++m)
      *(float4*)&sm.s.Bt[brow + 32 * m][bjq * 8] = br[m];
    // compute P tile (f32 scores, bf16 pack)
    {
      const float w2arr[8] = {w2a.x, w2a.y, w2a.z, w2a.w, w2b.x, w2b.y, w2b.z, w2b.w};
      short8 pv;
#pragma unroll
      for (int u = 0; u < 8; ++u) {
        float e = wh1r + w2arr[u];
        e = e > 0.f ? e : 0.01f * e;
        const float p = (mcur & (1u << u)) ? __expf(e) : 0.f;
        psum += p;
        pv[u] = (short)f2bf(p);
      }
      *(short8*)&sm.s.Pt[pi][pq * 8] = pv;
    }
    // prefetch next tile (hidden under MFMA phase)
    if (tile + 1 < ntiles) {
      const int j1 = jbase + (tile + 1) * 64;
      mcur = mp[(tile + 1) * 8 + pq];
#pragma unroll
      for (int m = 0; m < 4; ++m)
        br[m] = *(const float4*)&whT[(size_t)(brow + 32 * m) * NV + j1 + bjq * 8];
      w2a = *(const float4*)&wh2[j1 + pq * 8];
      w2b = *(const float4*)&wh2[j1 + pq * 8 + 4];
    }
    __syncthreads();
    // MFMA: wave wv owns cols wv*32..+31
#pragma unroll
    for (int ks = 0; ks < 2; ++ks) {
      const short8 a0 = *(const short8*)&sm.s.Pt[l15][ks * 32 + lg * 8];
      const short8 a1f = *(const short8*)&sm.s.Pt[16 + l15][ks * 32 + lg * 8];
      const short8 b0 = *(const short8*)&sm.s.Bt[wv * 32 + l15][ks * 32 + lg * 8];
      const short8 b1f = *(const short8*)&sm.s.Bt[wv * 32 + 16 + l15][ks * 32 + lg * 8];
      acc[0][0] = __builtin_amdgcn_mfma_f32_16x16x32_bf16(a0, b0, acc[0][0], 0, 0, 0);
      acc[0][1] = __builtin_amdgcn_mfma_f32_16x16x32_bf16(a0, b1f, acc[0][1], 0, 0, 0);
      acc[1][0] = __builtin_amdgcn_mfma_f32_16x16x32_bf16(a1f, b0, acc[1][0], 0, 0, 0);
      acc[1][1] = __builtin_amdgcn_mfma_f32_16x16x32_bf16(a1f, b1f, acc[1][1], 0, 0, 0);
    }
  }

  // partial row sums over this j-slice
#pragma unroll
  for (int off = 4; off > 0; off >>= 1) psum += __shfl_down(psum, off, 8);
  if (pq == 0) psum_p[(size_t)blockIdx.y * NV + i0 + pi] = psum;

  // epilogue: bounce acc through LDS, store fully coalesced
  __syncthreads();  // Bt/Pt dead
#pragma unroll
  for (int ih = 0; ih < 2; ++ih)
#pragma unroll
    for (int ct = 0; ct < 2; ++ct)
#pragma unroll
      for (int r = 0; r < 4; ++r)
        sm.epi[16 * ih + lg * 4 + r][wv * 32 + 16 * ct + l15] = acc[ih][ct][r];
  __syncthreads();
  {
    const size_t obase = ((size_t)blockIdx.y * NV + i0) * MOUT;
#pragma unroll
    for (int k = 0; k < 4; ++k) {
      const int flat4 = k * 256 + t;          // float4 index in 32x128 tile
      const int row = flat4 >> 5;
      const int c4 = (flat4 & 31) << 2;
      const float4 v = *(const float4*)&sm.epi[row][c4];
      *(float4*)&out_p[obase + (size_t)flat4 * 4] = v;
    }
  }
}

// ---------------- kernel 4: combine partials, normalize, ELU ----------------
__global__ __launch_bounds__(256) void k_comb(const float* __restrict__ out_p,
                                              const float* __restrict__ psum_p,
                                              float* __restrict__ out, int S) {
  const int idx = (blockIdx.x * 256 + threadIdx.x) * 4;
  const int n = idx >> 7;  // MOUT = 128
  float denom = 0.f;
  for (int s = 0; s < S; ++s) denom += psum_p[(size_t)s * NV + n];
  float4 acc = {0.f, 0.f, 0.f, 0.f};
  for (int s = 0; s < S; ++s) {
    const float4 v = *(const float4*)&out_p[(size_t)s * NV * MOUT + idx];
    acc.x += v.x; acc.y += v.y; acc.z += v.z; acc.w += v.w;
  }
  const float inv = 1.f / denom;
  float4 o;
  o.x = elu1(acc.x * inv);
  o.y = elu1(acc.y * inv);
  o.z = elu1(acc.z * inv);
  o.w = elu1(acc.w * inv);
  *(float4*)&out[idx] = o;
}

extern "C" void kernel_launch(void* const* d_in, const int* in_sizes, int n_in,
                              void* d_out, int out_size, void* d_ws, size_t ws_size,
                              hipStream_t stream) {
  const float* h  = (const float*)d_in[0];
  const int* adj  = (const int*)d_in[1];
  const float* w  = (const float*)d_in[2];
  const float* a1 = (const float*)d_in[3];
  const float* a2 = (const float*)d_in[4];
  float* out = (float*)d_out;

  char* ws = (char*)d_ws;
  // layout: [whT 2MB][wh1][wh2][psum_p 8*32KB][maskb 8MB][region: wh 4MB aliased by out_p]
  unsigned short* whT = (unsigned short*)ws;
  size_t off = (size_t)MOUT * NV * 2;
  float* wh1 = (float*)(ws + off); off += (size_t)NV * 4;
  float* wh2 = (float*)(ws + off); off += (size_t)NV * 4;
  float* psum_p = (float*)(ws + off); off += (size_t)8 * NV * 4;
  unsigned char* maskb = (unsigned char*)(ws + off); off += (size_t)NV * (NV / 8);
  float* region = (float*)(ws + off);
  float* wh = region;      // dead after k_tr
  float* out_p = region;   // S slabs of [NV][MOUT] f32

  int S = 8;
  while (S > 1 && off + (size_t)S * NV * MOUT * 4 > ws_size) S >>= 1;

  k_pack<<<NV / 4, 256, 0, stream>>>(adj, maskb);
  k_wh<<<NV / 32, 256, 0, stream>>>(h, w, a1, a2, wh, wh1, wh2);
  k_tr<<<NV / 64, 256, 0, stream>>>(wh, whT);
  k_attn_p<<<dim3(NV / 32, S), 256, 0, stream>>>(whT, maskb, wh1, wh2, out_p, psum_p, 128 / S);
  k_comb<<<(NV * MOUT / 4) / 256, 256, 0, stream>>>(out_p, psum_p, out, S);
}

// Round 4
// 183.264 us; speedup vs baseline: 1.8618x; 1.3659x over previous
//
#include <hip/hip_runtime.h>
#include <cstdint>
#include <cstddef>

#define NV    8192   // nodes
#define KIN   512    // in features
#define MOUT  128    // out features

typedef __attribute__((ext_vector_type(4))) float f32x4;
typedef __attribute__((ext_vector_type(8))) short short8;

__device__ __forceinline__ unsigned short f2bf(float x) {
  unsigned int u = __float_as_uint(x);
  return (unsigned short)((u + 0x7fffu + ((u >> 16) & 1u)) >> 16);  // RNE
}
__device__ __forceinline__ float elu1(float x) { return x > 0.f ? x : expm1f(x); }

// ---------------- kernel 1: wh = h @ w^T  (fp32) + fused wh1/wh2 ----------------
__global__ __launch_bounds__(256) void k_wh(const float* __restrict__ h,
                                            const float* __restrict__ w,
                                            const float* __restrict__ a1,
                                            const float* __restrict__ a2,
                                            float* __restrict__ wh,
                                            float* __restrict__ wh1,
                                            float* __restrict__ wh2) {
  __shared__ __align__(16) float hT[64][36];
  __shared__ __align__(16) float wT[64][128];
  const int t = threadIdx.x;
  const int row0 = blockIdx.x * 32;
  const int hr = t >> 3, hu = t & 7;
  const int wc = t >> 1, whalf = t & 1;
  const int cg = t & 31, rg = t >> 5;
  const int c0 = cg * 4, r0 = rg * 4;
  float acc[4][4] = {};

  for (int kt = 0; kt < 8; ++kt) {
    const int k0 = kt * 64;
    __syncthreads();
#pragma unroll
    for (int v = 0; v < 8; ++v)
      hT[hu + 8 * v][hr] = h[(size_t)(row0 + hr) * KIN + k0 + hu + 8 * v];
#pragma unroll
    for (int mv = 0; mv < 8; ++mv) {
      const float4 wv = *(const float4*)&w[(size_t)wc * KIN + k0 + whalf * 32 + mv * 4];
      wT[whalf * 32 + mv * 4 + 0][wc] = wv.x;
      wT[whalf * 32 + mv * 4 + 1][wc] = wv.y;
      wT[whalf * 32 + mv * 4 + 2][wc] = wv.z;
      wT[whalf * 32 + mv * 4 + 3][wc] = wv.w;
    }
    __syncthreads();
#pragma unroll 8
    for (int kk = 0; kk < 64; ++kk) {
      const float4 hv = *(const float4*)&hT[kk][r0];
      const float4 wv = *(const float4*)&wT[kk][c0];
      const float hvv[4] = {hv.x, hv.y, hv.z, hv.w};
      const float wvv[4] = {wv.x, wv.y, wv.z, wv.w};
#pragma unroll
      for (int i = 0; i < 4; ++i)
#pragma unroll
        for (int j = 0; j < 4; ++j)
          acc[i][j] = fmaf(hvv[i], wvv[j], acc[i][j]);
    }
  }

  const float4 a1v = *(const float4*)&a1[c0];
  const float4 a2v = *(const float4*)&a2[c0];
#pragma unroll
  for (int i = 0; i < 4; ++i) {
    float4 o;
    o.x = acc[i][0]; o.y = acc[i][1]; o.z = acc[i][2]; o.w = acc[i][3];
    *(float4*)&wh[(size_t)(row0 + r0 + i) * MOUT + c0] = o;
    float s1 = acc[i][0] * a1v.x + acc[i][1] * a1v.y + acc[i][2] * a1v.z + acc[i][3] * a1v.w;
    float s2 = acc[i][0] * a2v.x + acc[i][1] * a2v.y + acc[i][2] * a2v.z + acc[i][3] * a2v.w;
#pragma unroll
    for (int off = 16; off > 0; off >>= 1) {
      s1 += __shfl_down(s1, off, 32);
      s2 += __shfl_down(s2, off, 32);
    }
    if (cg == 0) {
      wh1[row0 + r0 + i] = s1;
      wh2[row0 + r0 + i] = s2;
    }
  }
}

// ---------------- kernel 2: fragB = bf16(wh) in MFMA-fragment order ----------------
// fragB[jt][cg][ks][lane][e] = bf16(wh[jt*64 + ks*32 + (lane>>4)*8 + e][cg*16 + (lane&15)])
// grid 128 x 256; per block: 64 j-rows x 128 c, LDS transpose, coalesced frag writes.
__global__ __launch_bounds__(256) void k_tr(const float* __restrict__ wh,
                                            unsigned short* __restrict__ fragB) {
  __shared__ __align__(16) unsigned short ldsT[128][72];
  const int t = threadIdx.x;
  const int j0 = blockIdx.x * 64;
  {
    const int jr = t >> 2, q = t & 3;
#pragma unroll
    for (int mv = 0; mv < 8; ++mv) {
      const float4 v = *(const float4*)&wh[(size_t)(j0 + jr) * MOUT + q * 32 + mv * 4];
      ldsT[q * 32 + mv * 4 + 0][jr] = f2bf(v.x);
      ldsT[q * 32 + mv * 4 + 1][jr] = f2bf(v.y);
      ldsT[q * 32 + mv * 4 + 2][jr] = f2bf(v.z);
      ldsT[q * 32 + mv * 4 + 3][jr] = f2bf(v.w);
    }
  }
  __syncthreads();
  {
#pragma unroll
    for (int k = 0; k < 4; ++k) {
      const int K = k * 256 + t;              // 0..1023 frag-chunk id
      const int cg = K >> 7, ks = (K >> 6) & 1, ln = K & 63;
      const int lg = ln >> 4, l15 = ln & 15;
      const short8 v = *(const short8*)&ldsT[cg * 16 + l15][ks * 32 + lg * 8];
      *(short8*)&fragB[((size_t)blockIdx.x * 1024 + K) * 8] = v;
    }
  }
}

// ---------------- kernel 3: barrier-free partial attention + PV (bf16 MFMA) ----------------
// grid (256, S) x 256 thr. Wave wv=(ih,ch): 16 i-rows (ih half) x 64 c-cols (ch half).
// Each wave computes its own P fragment in registers (redundant exp across ch) and
// reads B fragments directly from fragment-ordered global (L2). No LDS, no barriers.
__global__ __launch_bounds__(256, 4) void k_attn_p(const unsigned short* __restrict__ fragB,
                                                   const int* __restrict__ adj,
                                                   const float* __restrict__ wh1,
                                                   const float* __restrict__ wh2,
                                                   float* __restrict__ out_p,
                                                   float* __restrict__ psum_p,
                                                   int ntiles) {
  const int t = threadIdx.x;
  const int i0 = blockIdx.x * 32;
  const int jbase = blockIdx.y * ntiles * 64;
  const int lane = t & 63;
  const int wv = t >> 6;
  const int ih = wv & 1, ch = wv >> 1;
  const int l15 = lane & 15, lg = lane >> 4;

  const int row = i0 + ih * 16 + l15;
  const float wh1r = wh1[row];
  const int* aptr = adj + (size_t)row * NV + lg * 8;

  f32x4 acc[4] = {};
  float psum = 0.f;

  // prologue: issue adj loads for tile 0
  int4 a0 = *(const int4*)&aptr[jbase];
  int4 a1 = *(const int4*)&aptr[jbase + 4];
  int4 a2 = *(const int4*)&aptr[jbase + 32];
  int4 a3 = *(const int4*)&aptr[jbase + 32 + 4];

  for (int it = 0; it < ntiles; ++it) {
    const int j0 = jbase + it * 64;
    const size_t jt = (size_t)(j0 >> 6);
    // compress current adj regs -> 16-bit mask (bit = ks*8 + e)
    const unsigned int m =
        ((a0.x > 0) ? 0x1u : 0u)    | ((a0.y > 0) ? 0x2u : 0u)    |
        ((a0.z > 0) ? 0x4u : 0u)    | ((a0.w > 0) ? 0x8u : 0u)    |
        ((a1.x > 0) ? 0x10u : 0u)   | ((a1.y > 0) ? 0x20u : 0u)   |
        ((a1.z > 0) ? 0x40u : 0u)   | ((a1.w > 0) ? 0x80u : 0u)   |
        ((a2.x > 0) ? 0x100u : 0u)  | ((a2.y > 0) ? 0x200u : 0u)  |
        ((a2.z > 0) ? 0x400u : 0u)  | ((a2.w > 0) ? 0x800u : 0u)  |
        ((a3.x > 0) ? 0x1000u : 0u) | ((a3.y > 0) ? 0x2000u : 0u) |
        ((a3.z > 0) ? 0x4000u : 0u) | ((a3.w > 0) ? 0x8000u : 0u);
    // issue next tile's adj loads (HBM latency hidden across full iteration)
    if (it + 1 < ntiles) {
      const int jn = j0 + 64;
      a0 = *(const int4*)&aptr[jn];
      a1 = *(const int4*)&aptr[jn + 4];
      a2 = *(const int4*)&aptr[jn + 32];
      a3 = *(const int4*)&aptr[jn + 32 + 4];
    }
    // issue B-fragment loads (coalesced 1 KB each, L2-resident)
    short8 bf[8];
#pragma unroll
    for (int ks = 0; ks < 2; ++ks)
#pragma unroll
      for (int cgl = 0; cgl < 4; ++cgl) {
        const int cgg = ch * 4 + cgl;
        bf[ks * 4 + cgl] =
            *(const short8*)&fragB[(((jt * 8 + cgg) * 2 + ks) * 64 + lane) * 8];
      }
    // P compute -> A fragments in registers
    short8 af[2];
#pragma unroll
    for (int ks = 0; ks < 2; ++ks) {
      const float4 wa = *(const float4*)&wh2[j0 + ks * 32 + lg * 8];
      const float4 wb = *(const float4*)&wh2[j0 + ks * 32 + lg * 8 + 4];
      const float w2v[8] = {wa.x, wa.y, wa.z, wa.w, wb.x, wb.y, wb.z, wb.w};
      short8 pv;
#pragma unroll
      for (int e = 0; e < 8; ++e) {
        float x = wh1r + w2v[e];
        x = x > 0.f ? x : 0.01f * x;
        const float p = ((m >> (ks * 8 + e)) & 1u) ? __expf(x) : 0.f;
        psum += p;
        pv[e] = (short)f2bf(p);
      }
      af[ks] = pv;
    }
    // MFMA accumulate
#pragma unroll
    for (int ks = 0; ks < 2; ++ks) {
      acc[0] = __builtin_amdgcn_mfma_f32_16x16x32_bf16(af[ks], bf[ks * 4 + 0], acc[0], 0, 0, 0);
      acc[1] = __builtin_amdgcn_mfma_f32_16x16x32_bf16(af[ks], bf[ks * 4 + 1], acc[1], 0, 0, 0);
      acc[2] = __builtin_amdgcn_mfma_f32_16x16x32_bf16(af[ks], bf[ks * 4 + 2], acc[2], 0, 0, 0);
      acc[3] = __builtin_amdgcn_mfma_f32_16x16x32_bf16(af[ks], bf[ks * 4 + 3], acc[3], 0, 0, 0);
    }
  }

  // row sums: reduce over lg groups (lanes 16 apart share l15)
  psum += __shfl_xor(psum, 16, 64);
  psum += __shfl_xor(psum, 32, 64);
  if (ch == 0 && lg == 0)
    psum_p[(size_t)blockIdx.y * NV + row] = psum;

  // store unnormalized partial tile (C/D: col=l15, row=lg*4+r)
  const size_t ob = ((size_t)blockIdx.y * NV + i0 + ih * 16) * MOUT + ch * 64;
#pragma unroll
  for (int cgl = 0; cgl < 4; ++cgl)
#pragma unroll
    for (int r = 0; r < 4; ++r)
      out_p[ob + (size_t)(lg * 4 + r) * MOUT + cgl * 16 + l15] = acc[cgl][r];
}

// ---------------- kernel 4: combine partials, normalize, ELU ----------------
__global__ __launch_bounds__(256) void k_comb(const float* __restrict__ out_p,
                                              const float* __restrict__ psum_p,
                                              float* __restrict__ out, int S) {
  const int idx = (blockIdx.x * 256 + threadIdx.x) * 4;
  const int n = idx >> 7;  // MOUT = 128
  float denom = 0.f;
  for (int s = 0; s < S; ++s) denom += psum_p[(size_t)s * NV + n];
  float4 acc = {0.f, 0.f, 0.f, 0.f};
  for (int s = 0; s < S; ++s) {
    const float4 v = *(const float4*)&out_p[(size_t)s * NV * MOUT + idx];
    acc.x += v.x; acc.y += v.y; acc.z += v.z; acc.w += v.w;
  }
  const float inv = 1.f / denom;
  float4 o;
  o.x = elu1(acc.x * inv);
  o.y = elu1(acc.y * inv);
  o.z = elu1(acc.z * inv);
  o.w = elu1(acc.w * inv);
  *(float4*)&out[idx] = o;
}

extern "C" void kernel_launch(void* const* d_in, const int* in_sizes, int n_in,
                              void* d_out, int out_size, void* d_ws, size_t ws_size,
                              hipStream_t stream) {
  const float* h  = (const float*)d_in[0];
  const int* adj  = (const int*)d_in[1];
  const float* w  = (const float*)d_in[2];
  const float* a1 = (const float*)d_in[3];
  const float* a2 = (const float*)d_in[4];
  float* out = (float*)d_out;

  char* ws = (char*)d_ws;
  // layout: [fragB 2MB][wh1][wh2][psum_p 8*32KB][region: wh 4MB aliased by out_p slabs]
  unsigned short* fragB = (unsigned short*)ws;
  size_t off = (size_t)MOUT * NV * 2;
  float* wh1 = (float*)(ws + off); off += (size_t)NV * 4;
  float* wh2 = (float*)(ws + off); off += (size_t)NV * 4;
  float* psum_p = (float*)(ws + off); off += (size_t)8 * NV * 4;
  float* region = (float*)(ws + off);
  float* wh = region;      // dead after k_tr
  float* out_p = region;   // S slabs of [NV][MOUT] f32

  int S = 4;
  while (S > 1 && off + (size_t)S * NV * MOUT * 4 > ws_size) S >>= 1;

  k_wh<<<NV / 32, 256, 0, stream>>>(h, w, a1, a2, wh, wh1, wh2);
  k_tr<<<NV / 64, 256, 0, stream>>>(wh, fragB);
  k_attn_p<<<dim3(NV / 32, S), 256, 0, stream>>>(fragB, adj, wh1, wh2, out_p, psum_p, 128 / S);
  k_comb<<<(NV * MOUT / 4) / 256, 256, 0, stream>>>(out_p, psum_p, out, S);
}